// Round 2
// baseline (271.612 us; speedup 1.0000x reference)
//
#include <hip/hip_runtime.h>
#include <hip/hip_bf16.h>

// Problem: pooled = tanh(hs @ W^T + b); out0 = pooled[:,0]; out1 = span-means;
// out2 = zeros(N,S).  N=64, L=512, H=768, S=16. Inputs fp32, d_out fp32.
//
// R7: R6 (fused fp32-A staging, in-register bf16 convert) + deep pipeline:
//  - 3 LDS stages, prefetch distance 2.
//  - Counted s_waitcnt vmcnt(6) + raw s_barrier (one asm, memory clobber)
//    instead of __syncthreads' vmcnt(0) drain: loads stay in flight across
//    two full compute phases (~500+ cyc) covering L2/HBM latency.
//  - s_setprio(1) around the MFMA cluster (T5; phase split now exists).
// vmcnt ledger: at iter-k top outstanding = stage(k) 6 + stage(k+1) 6;
// vmcnt(6) retires stage(k). Last iter: vmcnt(0). stage(k+2) -> buf (k+2)%3
// == (k-1)%3 is issued only after barrier(k), which all waves reach only
// after consuming their iter-(k-1) ds_reads -> no overwrite race.
#define NPASS 64
#define LSEQ  512
#define HDIM  768
#define NSPAN 16
#define MTOT  (NPASS*LSEQ)                     // 32768
#define OFF_SENT (NPASS*HDIM)                  // 49152
#define W_ELEMS (HDIM*HDIM)                    // 589824

#define BM 128
#define BN 128
#define BK 32
#define NK (HDIM/BK)                           // 24 K-iterations
#define NSTAGE 3

typedef __bf16 bf16x8 __attribute__((ext_vector_type(8)));
typedef __bf16 bf16x4 __attribute__((ext_vector_type(4)));
typedef float  f32x4  __attribute__((ext_vector_type(4)));

__device__ inline unsigned short f2bf(float f) {
  __hip_bfloat16 h = __float2bfloat16(f);   // RNE
  unsigned short u; __builtin_memcpy(&u, &h, 2); return u;
}

// tanh via v_exp_f32: ~7 VALU ops vs ~25 for libm tanhf. |err| < 1e-6 rel,
// far inside the 2% threshold (bf16 input rounding dominates at 6e-3).
__device__ inline float fast_tanh(float x) {
  const float ax = fabsf(x);
  const float t  = __expf(-2.0f * ax);                  // v_exp_f32 path
  const float r  = (1.0f - t) * __builtin_amdgcn_rcpf(1.0f + t);
  return copysignf(r, x);
}

// 8x fp32 -> bf16x8 fragment (RNE via fptrunc; compiler emits cvt_pk pairs).
__device__ inline bf16x8 cvt8(f32x4 lo, f32x4 hi) {
  union { bf16x4 h[2]; bf16x8 v; } u;
  u.h[0] = __builtin_convertvector(lo, bf16x4);
  u.h[1] = __builtin_convertvector(hi, bf16x4);
  return u.v;
}

// fp32 -> bf16 one-shot convert of W only. 8 elems/thread, 16B stores.
__global__ __launch_bounds__(256) void convert_w_kernel(
    const float* __restrict__ W, unsigned short* __restrict__ Wb)
{
  const int i = (blockIdx.x * 256 + threadIdx.x) * 8;
  const float4 a = *(const float4*)(W + i);
  const float4 b = *(const float4*)(W + i + 4);
  union { unsigned short us[8]; uint4 v; } o;
  o.us[0]=f2bf(a.x); o.us[1]=f2bf(a.y); o.us[2]=f2bf(a.z); o.us[3]=f2bf(a.w);
  o.us[4]=f2bf(b.x); o.us[5]=f2bf(b.y); o.us[6]=f2bf(b.z); o.us[7]=f2bf(b.w);
  *(uint4*)(Wb + i) = o.v;
}

// fp32-A x bf16-W NT GEMM + fused tanh/pool epilogue.
// Grid: x = M-tile (256), y = N-tile (6); M fast => same-A blocks same XCD.
__global__ __launch_bounds__(256) void gemm_fused_kernel(
    const float* __restrict__ A,              // (32768, 768) fp32
    const unsigned short* __restrict__ Wb,    // (768, 768) bf16
    const float* __restrict__ bias,
    const int* __restrict__ spans,
    float* __restrict__ out)
{
  __shared__ __align__(16) float          As[NSTAGE][BM*BK]; // 3 x 16 KB fp32
  __shared__ __align__(16) unsigned short Bs[NSTAGE][BN*BK]; // 3 x  8 KB bf16
  __shared__ int   sp_st[NSPAN], sp_en[NSPAN];
  __shared__ float inv_s[NSPAN];
  __shared__ short sid_l[BM];      // local row -> span id (-1 none)
  __shared__ float bias_s[BN];

  const int tid  = threadIdx.x;
  const int wave = tid >> 6;
  const int lane = tid & 63;
  const int quad = lane >> 4;
  const int lr   = lane & 15;
  const int wm   = wave >> 1;
  const int wn   = wave & 1;
  const int tile_m = blockIdx.x * BM;
  const int tile_n = blockIdx.y * BN;
  const int npass  = tile_m >> 9;       // passage index
  const int l0     = tile_m & 511;      // first local seq position

  // Stage K-slice k into buffer buf. 24 x 1KB segments (16 A fp32, 8 B bf16),
  // 6 per wave -> 6 gload_lds per thread per stage (vmcnt ledger unit).
  // gload_lds writes LINEAR (lane*16B); the global source granule is
  // pre-swizzled so that LDS(row, g) holds global(row, g ^ f(row)):
  //   A: f(row) = row & 7    (8 x 16B granules per 128 B fp32 row)
  //   B: f(row) = (row>>1)&3 (4 x 16B granules per 64 B bf16 row)
  auto stage = [&](int k, int buf) {
    const int k0 = k * BK;
    #pragma unroll
    for (int j = 0; j < 6; ++j) {
      const int seg = j * 4 + wave;          // wave-uniform 0..23
      if (seg < 16) {
        const int row = seg * 8 + (lane >> 3);
        const int gs  = (lane & 7) ^ ((lane >> 3) & 7);
        const float* g = A + (size_t)(tile_m + row) * HDIM + (k0 + gs * 4);
        __builtin_amdgcn_global_load_lds(
            (const __attribute__((address_space(1))) void*)g,
            (__attribute__((address_space(3))) void*)(As[buf] + seg * 256),
            16, 0, 0);
      } else {
        const int s2  = seg - 16;
        const int row = s2 * 16 + (lane >> 2);
        const int gs  = (lane & 3) ^ ((lane >> 3) & 3);
        const unsigned short* g =
            Wb + (size_t)(tile_n + row) * HDIM + (k0 + gs * 8);
        __builtin_amdgcn_global_load_lds(
            (const __attribute__((address_space(1))) void*)g,
            (__attribute__((address_space(3))) void*)(Bs[buf] + s2 * 512),
            16, 0, 0);
      }
    }
  };

  // Prologue: stage slices 0 and 1, fill tables; __syncthreads drains
  // vmcnt(0) once (unavoidable for slice 0 anyway) and publishes tables.
  stage(0, 0);
  stage(1, 1);
  if (tid < NSPAN) {
    const int st = spans[(npass * NSPAN + tid) * 2 + 0];
    const int en = spans[(npass * NSPAN + tid) * 2 + 1];
    sp_st[tid] = st; sp_en[tid] = en; inv_s[tid] = 1.0f / (float)(en - st);
  }
  if (tid >= 128 && tid < 128 + BN) bias_s[tid - 128] = bias[tile_n + tid - 128];
  __syncthreads();
  // sid_l written here, first read in epilogue (after many barriers).
  if (tid < BM) {
    const int l = l0 + tid;
    short s = -1;
    #pragma unroll
    for (int i = 0; i < NSPAN; ++i)
      if (l >= sp_st[i] && l < sp_en[i]) s = (short)i;
    sid_l[tid] = s;
  }

  f32x4 acc[4][4];
  #pragma unroll
  for (int i = 0; i < 4; ++i)
    #pragma unroll
    for (int j = 0; j < 4; ++j)
      acc[i][j] = (f32x4){0.f, 0.f, 0.f, 0.f};

  for (int k = 0; k < NK; ++k) {
    const int cur = k % NSTAGE;

    // Counted drain: retire stage(k), leave stage(k+1) in flight.
    // Single asm: compiler cannot move LDS reads or gload_lds across it.
    if (k == NK - 1) asm volatile("s_waitcnt vmcnt(0)\n\ts_barrier" ::: "memory");
    else             asm volatile("s_waitcnt vmcnt(6)\n\ts_barrier" ::: "memory");

    // Fragments: A-operand A[m=lane&15][k=quad*8+j]; B-operand B[k][n=lane&15].
    // Swizzled reads (same XOR as the staged layout).
    bf16x8 af[4], bfr[4];
    #pragma unroll
    for (int mt = 0; mt < 4; ++mt) {
      const int r  = wm * 64 + mt * 16 + lr;
      const int sw = r & 7;
      const float* base = As[cur] + r * BK;
      const f32x4 lo = *(const f32x4*)(base + (((quad * 2    ) ^ sw) * 4));
      const f32x4 hi = *(const f32x4*)(base + (((quad * 2 + 1) ^ sw) * 4));
      af[mt] = cvt8(lo, hi);
    }
    #pragma unroll
    for (int nt = 0; nt < 4; ++nt) {
      const int r = wn * 64 + nt * 16 + lr;
      const int g = quad ^ ((r >> 1) & 3);
      bfr[nt] = *(const bf16x8*)(Bs[cur] + (r * BK + g * 8));
    }

    // Prefetch distance 2: overwrites buf (k-1)%3, safe (see header comment).
    if (k + 2 < NK) stage(k + 2, (k + 2) % NSTAGE);

    __builtin_amdgcn_s_setprio(1);
    #pragma unroll
    for (int mt = 0; mt < 4; ++mt)
      #pragma unroll
      for (int nt = 0; nt < 4; ++nt)
        acc[mt][nt] = __builtin_amdgcn_mfma_f32_16x16x32_bf16(
            af[mt], bfr[nt], acc[mt][nt], 0, 0, 0);
    __builtin_amdgcn_s_setprio(0);
  }

  // Epilogue. C/D layout: col=lane&15, row=quad*4+reg (R3/R4-validated).
  // Sentence means: run-merged, pre-scaled atomic adds into pre-zeroed out.
  // No barrier needed: acc is register-resident, sid_l published in prologue.
  #pragma unroll
  for (int nt = 0; nt < 4; ++nt) {
    const int lcolo = wn * 64 + nt * 16 + lr;       // 0..127
    const int col   = tile_n + lcolo;
    const float bv  = bias_s[lcolo];
    float* sent_col = out + OFF_SENT + (size_t)(npass * NSPAN) * HDIM + col;
    #pragma unroll
    for (int mt = 0; mt < 4; ++mt) {
      const int rowbase = wm * 64 + mt * 16 + quad * 4;  // local row
      int prev = -1; float run = 0.f;
      #pragma unroll
      for (int r = 0; r < 4; ++r) {
        const int lrw = rowbase + r;
        const float v = fast_tanh(acc[mt][nt][r] + bv);
        if (l0 == 0 && lrw == 0) out[(size_t)npass * HDIM + col] = v;
        const int s = sid_l[lrw];
        if (s != prev) {
          if (prev >= 0) unsafeAtomicAdd(sent_col + (size_t)prev * HDIM, run * inv_s[prev]);
          prev = s; run = 0.f;
        }
        run += v;
      }
      if (prev >= 0) unsafeAtomicAdd(sent_col + (size_t)prev * HDIM, run * inv_s[prev]);
    }
  }
}

extern "C" void kernel_launch(void* const* d_in, const int* in_sizes, int n_in,
                              void* d_out, int out_size, void* d_ws, size_t ws_size,
                              hipStream_t stream) {
  const float* hs  = (const float*)d_in[0];  // (64,512,768) fp32
  const float* w   = (const float*)d_in[1];  // (768,768) fp32
  const float* bsc = (const float*)d_in[2];  // (768,) fp32
  // d_in[3] attention_mask unused
  const int* spans = (const int*)d_in[4];    // (64,16,2) int32
  float* out = (float*)d_out;

  unsigned short* Wb = (unsigned short*)d_ws;  // 1,179,648 B

  hipMemsetAsync(d_out, 0, (size_t)out_size * sizeof(float), stream);

  convert_w_kernel<<<dim3(W_ELEMS / 8 / 256), dim3(256), 0, stream>>>(w, Wb);

  dim3 grid(MTOT / BM, HDIM / BN);  // (256, 6): M fast -> A-tile sharers co-XCD
  gemm_fused_kernel<<<grid, dim3(256), 0, stream>>>(hs, Wb, bsc, spans, out);
}

// Round 3
// 241.941 us; speedup vs baseline: 1.1226x; 1.1226x over previous
//
#include <hip/hip_runtime.h>
#include <hip/hip_bf16.h>

// Problem: pooled = tanh(hs @ W^T + b); out0 = pooled[:,0]; out1 = span-means;
// out2 = zeros(N,S).  N=64, L=512, H=768, S=16. Inputs fp32, d_out fp32.
//
// R8: single-dispatch, zero-barrier-K-loop restructure.
//  - Block = (passage, 96-col N-tile). Grid 64x8=512 blocks, 512 threads.
//  - W slice (96x768) converted fp32->bf16 ONCE into LDS in the prologue
//    (reg-staged ds_write -> free XOR swizzle kg^=row&7, conflict-free
//    ds_read_b128 fragments). K-loop reads W from read-only LDS: NO barriers,
//    NO per-iter staging, NO vmcnt drains.
//  - A fragments loaded global->register directly (16 rows x 128 B coalesced
//    segments, prefetch-distance-1 in regs, fp32->bf16 cvt at use).
//  - Whole passage per block => span sums are block-local: LDS atomicAdd,
//    direct stores, no global atomics => no memset dispatch. Kernel writes
//    ALL outputs (incl. sentence_mask zeros). ONE dispatch total.
//  - XCD swizzle: 8 sibling N-tile blocks of a passage land consecutive on
//    one XCD => passage's 1.5 MB A-slice is L2-resident across siblings.
#define NPASS 64
#define LSEQ  512
#define HDIM  768
#define NSPAN 16
#define OFF_SENT (NPASS*HDIM)                     // 49152
#define OFF_MASK (OFF_SENT + NPASS*NSPAN*HDIM)    // 835584

#define BN   96
#define NTN  6                     // BN/16 fragments per wave
#define BK   32
#define NK   (HDIM/BK)             // 24
#define NTILES (HDIM/BN)           // 8
#define NBLK (NPASS*NTILES)        // 512
#define THREADS 512

typedef __bf16 bf16x8 __attribute__((ext_vector_type(8)));
typedef __bf16 bf16x4 __attribute__((ext_vector_type(4)));
typedef float  f32x4  __attribute__((ext_vector_type(4)));

// tanh via v_exp_f32: ~7 VALU ops vs ~25 for libm tanhf. |err| < 1e-6 rel,
// far inside the 2% threshold (bf16 input rounding dominates at 6e-3).
__device__ inline float fast_tanh(float x) {
  const float ax = fabsf(x);
  const float t  = __expf(-2.0f * ax);
  const float r  = (1.0f - t) * __builtin_amdgcn_rcpf(1.0f + t);
  return copysignf(r, x);
}

// 8x fp32 -> bf16x8 (RNE via fptrunc; compiler emits v_cvt_pk_bf16_f32 pairs).
__device__ inline bf16x8 cvt8(f32x4 lo, f32x4 hi) {
  union { bf16x4 h[2]; bf16x8 v; } u;
  u.h[0] = __builtin_convertvector(lo, bf16x4);
  u.h[1] = __builtin_convertvector(hi, bf16x4);
  return u.v;
}

__global__ __launch_bounds__(THREADS, 2) void fused_kernel(
    const float* __restrict__ A,        // (32768, 768) fp32
    const float* __restrict__ W,        // (768, 768) fp32, row o contiguous in h
    const float* __restrict__ bias,     // (768,)
    const int*   __restrict__ spans,    // (64,16,2)
    float* __restrict__ out)
{
  __shared__ __align__(16) unsigned short Wl[BN * HDIM];   // 147456 B bf16
  __shared__ float sent_lds[NSPAN][BN];                    // 6144 B
  __shared__ float inv_s[NSPAN];
  __shared__ float bias_s[BN];
  __shared__ short sid_l[LSEQ];                            // 1024 B
  // total ~155 KB < 160 KB -> 1 block/CU, 8 waves (2/SIMD)

  const int tid = threadIdx.x;
  const int b   = blockIdx.x;
  // XCD swizzle (bijective, 512 = 64*8): siblings of a passage consecutive
  // per XCD under the b%8 round-robin heuristic. Perf-only.
  const int xcd = b & 7;
  const int t   = b >> 3;                 // 0..63 per XCD
  const int p   = ((t >> 3) << 3) | xcd;  // passage 0..63
  const int ntb = t & 7;                  // N-tile 0..7
  const int tile_n = ntb * BN;

  // ---- Prologue (everything before the single barrier) ----

  // 1) Stage W slice: fp32 global -> cvt -> bf16 LDS, XOR-swizzled.
  //    Layout: Wl[wr][kg'] with kg' = kg ^ (wr&7) over 16B granules (8 bf16).
  //    9216 granules / 512 threads = 18 per thread, coalesced 32B loads.
  {
    const float* Wp = W + (size_t)tile_n * HDIM;
    #pragma unroll
    for (int j = 0; j < (BN * (HDIM / 8)) / THREADS; ++j) {
      const int g  = j * THREADS + tid;
      const int wr = g / (HDIM / 8);        // 0..95  (W row = output col)
      const int kg = g % (HDIM / 8);        // 0..95  (16B granule in K)
      const float* src = Wp + (size_t)wr * HDIM + kg * 8;
      const f32x4 lo = *(const f32x4*)src;
      const f32x4 hi = *(const f32x4*)(src + 4);
      const int kgs = kg ^ (wr & 7);
      *(bf16x8*)(Wl + (size_t)wr * HDIM + kgs * 8) = cvt8(lo, hi);
    }
  }

  // 2) Span tables. Each thread reads spans (uniform addrs -> scalar loads)
  //    into static-indexed regs; sid for its own row (tid == local row).
  {
    int st[NSPAN], en[NSPAN];
    #pragma unroll
    for (int i = 0; i < NSPAN; ++i) {
      st[i] = spans[(p * NSPAN + i) * 2 + 0];
      en[i] = spans[(p * NSPAN + i) * 2 + 1];
    }
    short s = -1;
    #pragma unroll
    for (int i = 0; i < NSPAN; ++i)
      if (tid >= st[i] && tid < en[i]) s = (short)i;
    sid_l[tid] = s;
  }
  if (tid < NSPAN)
    inv_s[tid] = 1.0f / (float)(spans[(p * NSPAN + tid) * 2 + 1] -
                                spans[(p * NSPAN + tid) * 2 + 0]);
  if (tid < BN) bias_s[tid] = bias[tile_n + tid];
  for (int i = tid; i < NSPAN * BN; i += THREADS) (&sent_lds[0][0])[i] = 0.f;

  __syncthreads();   // the ONLY barrier before the epilogue

  // ---- Zero-barrier K-loop ----
  const int wave = tid >> 6;            // 0..7 -> rows [wave*64, wave*64+64)
  const int lane = tid & 63;
  const int quad = lane >> 4;
  const int lr   = lane & 15;

  // A-operand: lane holds A[row = base+mt*16+lr][k = k0+quad*8+j] (fp32->bf16).
  const float* Ab = A + ((size_t)p * LSEQ + wave * 64 + lr) * HDIM + quad * 8;

  f32x4 acc[4][NTN];
  #pragma unroll
  for (int mt = 0; mt < 4; ++mt)
    #pragma unroll
    for (int nt = 0; nt < NTN; ++nt)
      acc[mt][nt] = (f32x4){0.f, 0.f, 0.f, 0.f};

  f32x4 alo[4], ahi[4];
  #pragma unroll
  for (int mt = 0; mt < 4; ++mt) {
    const float* s0 = Ab + (size_t)mt * 16 * HDIM;
    alo[mt] = *(const f32x4*)s0;
    ahi[mt] = *(const f32x4*)(s0 + 4);
  }

  #pragma unroll
  for (int k = 0; k < NK; ++k) {
    // W fragments: Wl[wr=nt*16+lr][granule (4k+quad) ^ (lr&7)] -- the swizzle
    // granule is nt-independent ((nt*16)&7==0); banks: 8 slots x 2 lanes = free.
    bf16x8 wf[NTN];
    #pragma unroll
    for (int nt = 0; nt < NTN; ++nt) {
      const int wr = nt * 16 + lr;
      const int kg = (4 * k + quad) ^ (lr & 7);
      wf[nt] = *(const bf16x8*)(Wl + (size_t)wr * HDIM + kg * 8);
    }
    // Convert current A frags, then prefetch next k into the fp32 regs.
    bf16x8 abf[4];
    #pragma unroll
    for (int mt = 0; mt < 4; ++mt) abf[mt] = cvt8(alo[mt], ahi[mt]);
    if (k + 1 < NK) {
      #pragma unroll
      for (int mt = 0; mt < 4; ++mt) {
        const float* s1 = Ab + (size_t)mt * 16 * HDIM + (k + 1) * BK;
        alo[mt] = *(const f32x4*)s1;
        ahi[mt] = *(const f32x4*)(s1 + 4);
      }
    }
    __builtin_amdgcn_s_setprio(1);
    #pragma unroll
    for (int mt = 0; mt < 4; ++mt)
      #pragma unroll
      for (int nt = 0; nt < NTN; ++nt)
        acc[mt][nt] = __builtin_amdgcn_mfma_f32_16x16x32_bf16(
            abf[mt], wf[nt], acc[mt][nt], 0, 0, 0);
    __builtin_amdgcn_s_setprio(0);
  }

  // ---- Epilogue: C/D layout col=lane&15, row=quad*4+reg (validated). ----
  // Span sums: run-merged LDS atomicAdd (block-local; scaled at writeout).
  #pragma unroll
  for (int nt = 0; nt < NTN; ++nt) {
    const int col = nt * 16 + lr;            // 0..95
    const float bv = bias_s[col];
    #pragma unroll
    for (int mt = 0; mt < 4; ++mt) {
      const int rowbase = wave * 64 + mt * 16 + quad * 4;   // local row
      int prev = -1; float run = 0.f;
      #pragma unroll
      for (int r = 0; r < 4; ++r) {
        const int row = rowbase + r;
        const float v = fast_tanh(acc[mt][nt][r] + bv);
        if (row == 0) out[(size_t)p * HDIM + tile_n + col] = v;  // pooled[:,0]
        const int s = sid_l[row];
        if (s != prev) {
          if (prev >= 0) atomicAdd(&sent_lds[prev][col], run);
          prev = s; run = 0.f;
        }
        run += v;
      }
      if (prev >= 0) atomicAdd(&sent_lds[prev][col], run);
    }
  }
  __syncthreads();

  // Writeout: sentence means + sentence_mask zeros.
  for (int i = tid; i < NSPAN * BN; i += THREADS) {
    const int s = i / BN, c = i % BN;
    out[OFF_SENT + ((size_t)p * NSPAN + s) * HDIM + tile_n + c] =
        sent_lds[s][c] * inv_s[s];
  }
  if (ntb == 0 && tid < NSPAN) out[OFF_MASK + p * NSPAN + tid] = 0.f;
}

extern "C" void kernel_launch(void* const* d_in, const int* in_sizes, int n_in,
                              void* d_out, int out_size, void* d_ws, size_t ws_size,
                              hipStream_t stream) {
  const float* hs  = (const float*)d_in[0];  // (64,512,768) fp32
  const float* w   = (const float*)d_in[1];  // (768,768) fp32
  const float* bsc = (const float*)d_in[2];  // (768,) fp32
  // d_in[3] attention_mask unused
  const int* spans = (const int*)d_in[4];    // (64,16,2) int32

  fused_kernel<<<dim3(NBLK), dim3(THREADS), 0, stream>>>(
      hs, w, bsc, spans, (float*)d_out);
}

// Round 4
// 228.805 us; speedup vs baseline: 1.1871x; 1.0574x over previous
//
#include <hip/hip_runtime.h>
#include <hip/hip_bf16.h>

// Problem: pooled = tanh(hs @ W^T + b); out0 = pooled[:,0]; out1 = span-means;
// out2 = zeros(N,S).  N=64, L=512, H=768, S=16. Inputs fp32, d_out fp32.
//
// R9: R8 structure (single dispatch, W-in-LDS once, zero-barrier K-loop,
// block-local span epilogue) with DOUBLED TLP: 1024-thread blocks (16 waves
// = 4 waves/SIMD instead of 2). R8 was latency-bound at 550 GB/s because a
// 1-block/CU 8-wave block gives only 2 waves/SIMD and ~8 outstanding 16B
// A-loads per wave. Per-wave tile shrinks to 32 rows (mt=2): regs/wave
// ~110 < 128, so all 16 waves are resident (forced by the 1024-thread block).
#define NPASS 64
#define LSEQ  512
#define HDIM  768
#define NSPAN 16
#define OFF_SENT (NPASS*HDIM)                     // 49152
#define OFF_MASK (OFF_SENT + NPASS*NSPAN*HDIM)    // 835584

#define BN   96
#define NTN  6                     // BN/16 fragments per wave
#define BK   32
#define NK   (HDIM/BK)             // 24
#define NTILES (HDIM/BN)           // 8
#define NBLK (NPASS*NTILES)        // 512  (= 2 exact rounds on 256 CUs)
#define THREADS 1024
#define NMT  2                     // row-fragments per wave (32 rows/wave)

typedef __bf16 bf16x8 __attribute__((ext_vector_type(8)));
typedef __bf16 bf16x4 __attribute__((ext_vector_type(4)));
typedef float  f32x4  __attribute__((ext_vector_type(4)));

// tanh via v_exp_f32: ~7 VALU ops vs ~25 for libm tanhf. |err| < 1e-6 rel,
// far inside the 2% threshold (bf16 input rounding dominates at 6e-3).
__device__ inline float fast_tanh(float x) {
  const float ax = fabsf(x);
  const float t  = __expf(-2.0f * ax);
  const float r  = (1.0f - t) * __builtin_amdgcn_rcpf(1.0f + t);
  return copysignf(r, x);
}

// 8x fp32 -> bf16x8 (RNE via fptrunc; compiler emits v_cvt_pk_bf16_f32 pairs).
__device__ inline bf16x8 cvt8(f32x4 lo, f32x4 hi) {
  union { bf16x4 h[2]; bf16x8 v; } u;
  u.h[0] = __builtin_convertvector(lo, bf16x4);
  u.h[1] = __builtin_convertvector(hi, bf16x4);
  return u.v;
}

__global__ __launch_bounds__(THREADS, 4) void fused_kernel(
    const float* __restrict__ A,        // (32768, 768) fp32
    const float* __restrict__ W,        // (768, 768) fp32, row o contiguous in h
    const float* __restrict__ bias,     // (768,)
    const int*   __restrict__ spans,    // (64,16,2)
    float* __restrict__ out)
{
  __shared__ __align__(16) unsigned short Wl[BN * HDIM];   // 147456 B bf16
  __shared__ float sent_lds[NSPAN][BN];                    // 6144 B
  __shared__ float inv_s[NSPAN];
  __shared__ float bias_s[BN];
  __shared__ short sid_l[LSEQ];                            // 1024 B
  // total ~155 KB -> 1 block/CU, 16 waves (4/SIMD)

  const int tid = threadIdx.x;
  const int b   = blockIdx.x;
  // XCD swizzle (bijective, 512 = 64*8): 8 sibling N-tiles of a passage land
  // consecutive on one XCD -> passage's 1.5 MB A-slice L2/L3-shared.
  const int xcd = b & 7;
  const int t   = b >> 3;                 // 0..63 per XCD
  const int p   = ((t >> 3) << 3) | xcd;  // passage 0..63
  const int ntb = t & 7;                  // N-tile 0..7
  const int tile_n = ntb * BN;

  // ---- Prologue ----

  // 1) Stage W slice: fp32 global -> cvt -> bf16 LDS, XOR-swizzled.
  //    Layout: Wl[wr][kg'] with kg' = kg ^ (wr&7) over 16B granules (8 bf16).
  //    9216 granules / 1024 threads = 9 per thread, coalesced 32B loads.
  {
    const float* Wp = W + (size_t)tile_n * HDIM;
    #pragma unroll
    for (int j = 0; j < (BN * (HDIM / 8)) / THREADS; ++j) {
      const int g  = j * THREADS + tid;
      const int wr = g / (HDIM / 8);        // 0..95  (W row = output col)
      const int kg = g % (HDIM / 8);        // 0..95  (16B granule in K)
      const float* src = Wp + (size_t)wr * HDIM + kg * 8;
      const f32x4 lo = *(const f32x4*)src;
      const f32x4 hi = *(const f32x4*)(src + 4);
      const int kgs = kg ^ (wr & 7);
      *(bf16x8*)(Wl + (size_t)wr * HDIM + kgs * 8) = cvt8(lo, hi);
    }
  }

  // 2) Span tables; sid_l for rows 0..511 (tid==row for tid<512).
  if (tid < LSEQ) {
    int st[NSPAN], en[NSPAN];
    #pragma unroll
    for (int i = 0; i < NSPAN; ++i) {
      st[i] = spans[(p * NSPAN + i) * 2 + 0];
      en[i] = spans[(p * NSPAN + i) * 2 + 1];
    }
    short s = -1;
    #pragma unroll
    for (int i = 0; i < NSPAN; ++i)
      if (tid >= st[i] && tid < en[i]) s = (short)i;
    sid_l[tid] = s;
  }
  if (tid < NSPAN)
    inv_s[tid] = 1.0f / (float)(spans[(p * NSPAN + tid) * 2 + 1] -
                                spans[(p * NSPAN + tid) * 2 + 0]);
  if (tid >= 512 && tid < 512 + BN) bias_s[tid - 512] = bias[tile_n + tid - 512];
  for (int i = tid; i < NSPAN * BN; i += THREADS) (&sent_lds[0][0])[i] = 0.f;

  __syncthreads();   // the ONLY barrier before the epilogue

  // ---- Zero-barrier K-loop ----
  const int wave = tid >> 6;            // 0..15 -> rows [wave*32, wave*32+32)
  const int lane = tid & 63;
  const int quad = lane >> 4;
  const int lr   = lane & 15;

  // A-operand: lane holds A[row = base+mt*16+lr][k = k0+quad*8+j] (fp32->bf16).
  const float* Ab = A + ((size_t)p * LSEQ + wave * 32 + lr) * HDIM + quad * 8;

  f32x4 acc[NMT][NTN];
  #pragma unroll
  for (int mt = 0; mt < NMT; ++mt)
    #pragma unroll
    for (int nt = 0; nt < NTN; ++nt)
      acc[mt][nt] = (f32x4){0.f, 0.f, 0.f, 0.f};

  f32x4 alo[NMT], ahi[NMT];
  #pragma unroll
  for (int mt = 0; mt < NMT; ++mt) {
    const float* s0 = Ab + (size_t)mt * 16 * HDIM;
    alo[mt] = *(const f32x4*)s0;
    ahi[mt] = *(const f32x4*)(s0 + 4);
  }

  #pragma unroll
  for (int k = 0; k < NK; ++k) {
    // W fragments: Wl[wr=nt*16+lr][granule (4k+quad) ^ (lr&7)] -- swizzle
    // granule is nt-independent ((nt*16)&7==0); 8 slots x 2 lanes = free.
    bf16x8 wf[NTN];
    #pragma unroll
    for (int nt = 0; nt < NTN; ++nt) {
      const int wr = nt * 16 + lr;
      const int kg = (4 * k + quad) ^ (lr & 7);
      wf[nt] = *(const bf16x8*)(Wl + (size_t)wr * HDIM + kg * 8);
    }
    // Convert current A frags, then prefetch next k into the fp32 regs.
    bf16x8 abf[NMT];
    #pragma unroll
    for (int mt = 0; mt < NMT; ++mt) abf[mt] = cvt8(alo[mt], ahi[mt]);
    if (k + 1 < NK) {
      #pragma unroll
      for (int mt = 0; mt < NMT; ++mt) {
        const float* s1 = Ab + (size_t)mt * 16 * HDIM + (k + 1) * BK;
        alo[mt] = *(const f32x4*)s1;
        ahi[mt] = *(const f32x4*)(s1 + 4);
      }
    }
    __builtin_amdgcn_s_setprio(1);
    #pragma unroll
    for (int mt = 0; mt < NMT; ++mt)
      #pragma unroll
      for (int nt = 0; nt < NTN; ++nt)
        acc[mt][nt] = __builtin_amdgcn_mfma_f32_16x16x32_bf16(
            abf[mt], wf[nt], acc[mt][nt], 0, 0, 0);
    __builtin_amdgcn_s_setprio(0);
  }

  // ---- Epilogue: C/D layout col=lane&15, row=quad*4+reg (validated). ----
  // Span sums: run-merged LDS atomicAdd (block-local; scaled at writeout).
  #pragma unroll
  for (int nt = 0; nt < NTN; ++nt) {
    const int col = nt * 16 + lr;            // 0..95
    const float bv = bias_s[col];
    #pragma unroll
    for (int mt = 0; mt < NMT; ++mt) {
      const int rowbase = wave * 32 + mt * 16 + quad * 4;   // local row
      int prev = -1; float run = 0.f;
      #pragma unroll
      for (int r = 0; r < 4; ++r) {
        const int row = rowbase + r;
        const float v = fast_tanh(acc[mt][nt][r] + bv);
        if (row == 0) out[(size_t)p * HDIM + tile_n + col] = v;  // pooled[:,0]
        const int s = sid_l[row];
        if (s != prev) {
          if (prev >= 0) atomicAdd(&sent_lds[prev][col], run);
          prev = s; run = 0.f;
        }
        run += v;
      }
      if (prev >= 0) atomicAdd(&sent_lds[prev][col], run);
    }
  }
  __syncthreads();

  // Writeout: sentence means + sentence_mask zeros.
  for (int i = tid; i < NSPAN * BN; i += THREADS) {
    const int s = i / BN, c = i % BN;
    out[OFF_SENT + ((size_t)p * NSPAN + s) * HDIM + tile_n + c] =
        sent_lds[s][c] * inv_s[s];
  }
  if (ntb == 0 && tid < NSPAN) out[OFF_MASK + p * NSPAN + tid] = 0.f;
}

extern "C" void kernel_launch(void* const* d_in, const int* in_sizes, int n_in,
                              void* d_out, int out_size, void* d_ws, size_t ws_size,
                              hipStream_t stream) {
  const float* hs  = (const float*)d_in[0];  // (64,512,768) fp32
  const float* w   = (const float*)d_in[1];  // (768,768) fp32
  const float* bsc = (const float*)d_in[2];  // (768,) fp32
  // d_in[3] attention_mask unused
  const int* spans = (const int*)d_in[4];    // (64,16,2) int32

  fused_kernel<<<dim3(NBLK), dim3(THREADS), 0, stream>>>(
      hs, w, bsc, spans, (float*)d_out);
}